// Round 4
// baseline (106.146 us; speedup 1.0000x reference)
//
#include <hip/hip_runtime.h>
#include <cstdint>

typedef float f32x4 __attribute__((ext_vector_type(4)));
typedef unsigned short u16;

constexpr int Bv = 32;      // batch rows (M)
constexpr int Hv = 4096;    // hidden (K1, N2)
constexpr int Iv = 2048;    // intermediate
constexpr int N1 = 4096;    // 2*I

// ---------------------------------------------------------------------------
// fp4 e2m1 word (8 nibbles, LSB-first along K) -> 8 fp8 e4m3 bytes (k-order)
// Magnitude LUT (idx 0-7): 0x00,0x30,0x38,0x3C,0x40,0x44,0x48,0x4C; sign->bit7.
// 7 VALU per word. (e4m3fn: 0.5=0x30, 1=0x38, 1.5=0x3C, 2=0x40, 3=0x44,
// 4=0x48, 6=0x4C — verified by hand against bias-7 encoding.)
// ---------------------------------------------------------------------------
__device__ __forceinline__ long dec8(uint32_t w) {
  uint32_t lo = w & 0x07070707u;          // mag idx n0,n2,n4,n6
  uint32_t hi = (w >> 4) & 0x07070707u;   // mag idx n1,n3,n5,n7
  uint32_t me = __builtin_amdgcn_perm(0x4C484440u, 0x3C383000u, lo);
  uint32_t mo = __builtin_amdgcn_perm(0x4C484440u, 0x3C383000u, hi);
  uint32_t e  = me | ((w & 0x08080808u) << 4);   // even nibbles + sign
  uint32_t o  = mo | (w & 0x80808080u);          // odd nibbles + sign
  uint32_t d0 = __builtin_amdgcn_perm(o, e, 0x05010400u);  // n0,n1,n2,n3
  uint32_t d1 = __builtin_amdgcn_perm(o, e, 0x07030602u);  // n4,n5,n6,n7
  return (long)(((uint64_t)d1 << 32) | d0);
}

// ---------------------------------------------------------------------------
// K0: x f32 [32,4096] -> two fp8(e4m3) planes: xh = fp8(x), xl = fp8(x-xh).
// Two-term split: single fp8 (~3.6% rms) would fail the 2% absmax threshold;
// split residual brings activation error to ~0.4%.
// ---------------------------------------------------------------------------
__global__ __launch_bounds__(256) void k_prep(const float* __restrict__ x,
                                              uint32_t* __restrict__ xh,
                                              uint32_t* __restrict__ xl) {
  const int t = blockIdx.x * 256 + threadIdx.x;   // 16384 threads, 8 elems each
  const float* p = x + t * 8;
  f32x4 v0 = *(const f32x4*)p;
  f32x4 v1 = *(const f32x4*)(p + 4);
  float f[8] = {v0[0], v0[1], v0[2], v0[3], v1[0], v1[1], v1[2], v1[3]};
  uint32_t h0 = 0, h1 = 0;
  h0 = __builtin_amdgcn_cvt_pk_fp8_f32(f[0], f[1], h0, false);
  h0 = __builtin_amdgcn_cvt_pk_fp8_f32(f[2], f[3], h0, true);
  h1 = __builtin_amdgcn_cvt_pk_fp8_f32(f[4], f[5], h1, false);
  h1 = __builtin_amdgcn_cvt_pk_fp8_f32(f[6], f[7], h1, true);
  float r[8];
  r[0] = f[0] - __builtin_amdgcn_cvt_f32_fp8(h0, 0);
  r[1] = f[1] - __builtin_amdgcn_cvt_f32_fp8(h0, 1);
  r[2] = f[2] - __builtin_amdgcn_cvt_f32_fp8(h0, 2);
  r[3] = f[3] - __builtin_amdgcn_cvt_f32_fp8(h0, 3);
  r[4] = f[4] - __builtin_amdgcn_cvt_f32_fp8(h1, 0);
  r[5] = f[5] - __builtin_amdgcn_cvt_f32_fp8(h1, 1);
  r[6] = f[6] - __builtin_amdgcn_cvt_f32_fp8(h1, 2);
  r[7] = f[7] - __builtin_amdgcn_cvt_f32_fp8(h1, 3);
  uint32_t l0 = 0, l1 = 0;
  l0 = __builtin_amdgcn_cvt_pk_fp8_f32(r[0], r[1], l0, false);
  l0 = __builtin_amdgcn_cvt_pk_fp8_f32(r[2], r[3], l0, true);
  l1 = __builtin_amdgcn_cvt_pk_fp8_f32(r[4], r[5], l1, false);
  l1 = __builtin_amdgcn_cvt_pk_fp8_f32(r[6], r[7], l1, true);
  xh[t*2] = h0; xh[t*2+1] = h1;
  xl[t*2] = l0; xl[t*2+1] = l1;
}

// ---------------------------------------------------------------------------
// K1: hpart[kq][32][4096] = x[32, kq-quarter] @ dequant(W_gu)  (f32 partials)
// 256 wgs: 64-col n-tile x K-quarter(1024). 4 waves: colsub(2) x rowhalf(2).
// mfma_f32_16x16x32_fp8_fp8. Per 128-group: 4 K-steps into temp, then
// acc += f32scale * temp (exact scale application; 1 group = 128 = 4*K32).
// Layouts: A[m=lane&15][k=quad*8+j]; C/D col=lane&15, row=quad*4+reg.
// ---------------------------------------------------------------------------
__global__ __launch_bounds__(256) void k_gateup(
    const uint8_t* __restrict__ xh, const uint8_t* __restrict__ xl,
    const uint32_t* __restrict__ wp, const float* __restrict__ sc,
    float* __restrict__ hp) {
  const int nt = blockIdx.x >> 2;          // 0..63
  const int kq = blockIdx.x & 3;           // K quarter
  const int wid = threadIdx.x >> 6, lane = threadIdx.x & 63;
  const int q = lane >> 4, r = lane & 15;
  const int colsub = wid & 1, rowh = wid >> 1;
  const int n0 = nt * 64 + colsub * 32;
  const int nA = n0 + r, nB = n0 + 16 + r;
  const int m  = rowh * 16 + r;

  const uint8_t* pah = xh + m * Hv + kq * 1024 + q * 8;
  const uint8_t* pal = xl + m * Hv + kq * 1024 + q * 8;
  const uint32_t* pb = wp + (size_t)(kq * 128 + q) * N1;
  const float* psc = sc + kq * 8 * N1;

  f32x4 accA = {0,0,0,0}, accB = {0,0,0,0};

  for (int g = 0; g < 8; ++g) {            // 8 scale groups of 128
    f32x4 tA = {0,0,0,0}, tB = {0,0,0,0};
    #pragma unroll
    for (int st = 0; st < 4; ++st) {       // 4 x K=32 MFMA steps
      const int koff = g * 128 + st * 32;
      long Ah = *(const long*)(pah + koff);
      long Al = *(const long*)(pal + koff);
      const uint32_t* b = pb + (size_t)(g * 16 + st * 4) * N1;
      long BA = dec8(b[nA]);
      long BB = dec8(b[nB]);
      tA = __builtin_amdgcn_mfma_f32_16x16x32_fp8_fp8(Ah, BA, tA, 0, 0, 0);
      tA = __builtin_amdgcn_mfma_f32_16x16x32_fp8_fp8(Al, BA, tA, 0, 0, 0);
      tB = __builtin_amdgcn_mfma_f32_16x16x32_fp8_fp8(Ah, BB, tB, 0, 0, 0);
      tB = __builtin_amdgcn_mfma_f32_16x16x32_fp8_fp8(Al, BB, tB, 0, 0, 0);
    }
    const float sA = psc[g * N1 + nA];
    const float sB = psc[g * N1 + nB];
    #pragma unroll
    for (int j = 0; j < 4; ++j) {
      accA[j] = fmaf(sA, tA[j], accA[j]);
      accB[j] = fmaf(sB, tB[j], accB[j]);
    }
  }
  float* o = hp + (size_t)kq * (Bv * N1);
  #pragma unroll
  for (int j = 0; j < 4; ++j) {
    const int row = rowh * 16 + q * 4 + j;
    o[row * N1 + nA] = accA[j];
    o[row * N1 + nB] = accB[j];
  }
}

// ---------------------------------------------------------------------------
// K2: SwiGLU over 4 f32 partial planes -> two fp8 planes of act [32,2048].
// Clamp to +-440 (OCP e4m3 overflow->NaN armor; true |act| <~ 25).
// ---------------------------------------------------------------------------
__global__ __launch_bounds__(256) void k_swiglu(const float* __restrict__ hp,
                                                uint32_t* __restrict__ ah,
                                                uint32_t* __restrict__ al) {
  const int t = blockIdx.x * 256 + threadIdx.x;  // 16384 threads, 4 elems each
  const int m = t >> 9;
  const int c = (t & 511) * 4;
  constexpr int P = Bv * N1;
  const float* pg = hp + m * N1 + c;
  const float* pu = pg + Iv;
  f32x4 g = *(const f32x4*)pg + *(const f32x4*)(pg+P) + *(const f32x4*)(pg+2*P) + *(const f32x4*)(pg+3*P);
  f32x4 u = *(const f32x4*)pu + *(const f32x4*)(pu+P) + *(const f32x4*)(pu+2*P) + *(const f32x4*)(pu+3*P);
  float a[4];
  #pragma unroll
  for (int j = 0; j < 4; ++j) {
    float gv = g[j];
    float av = gv / (1.0f + __expf(-gv)) * u[j];
    a[j] = fminf(fmaxf(av, -440.0f), 440.0f);
  }
  uint32_t h = 0;
  h = __builtin_amdgcn_cvt_pk_fp8_f32(a[0], a[1], h, false);
  h = __builtin_amdgcn_cvt_pk_fp8_f32(a[2], a[3], h, true);
  float r0 = a[0] - __builtin_amdgcn_cvt_f32_fp8(h, 0);
  float r1 = a[1] - __builtin_amdgcn_cvt_f32_fp8(h, 1);
  float r2 = a[2] - __builtin_amdgcn_cvt_f32_fp8(h, 2);
  float r3 = a[3] - __builtin_amdgcn_cvt_f32_fp8(h, 3);
  uint32_t l = 0;
  l = __builtin_amdgcn_cvt_pk_fp8_f32(r0, r1, l, false);
  l = __builtin_amdgcn_cvt_pk_fp8_f32(r2, r3, l, true);
  ah[t] = h; al[t] = l;
}

// ---------------------------------------------------------------------------
// K3: out f32 [32][4096] = act[32,2048] @ dequant(W_down).
// 256 wgs x 16 cols. 4 waves: rowhalf(2) x K-half(2 x 1024). LDS-reduce.
// ---------------------------------------------------------------------------
__global__ __launch_bounds__(256) void k_down(
    const uint8_t* __restrict__ ah8, const uint8_t* __restrict__ al8,
    const uint32_t* __restrict__ wp, const float* __restrict__ sc,
    float* __restrict__ out) {
  __shared__ float lds[1024];
  const int n0 = blockIdx.x * 16;
  const int wid = threadIdx.x >> 6, lane = threadIdx.x & 63;
  const int q = lane >> 4, r = lane & 15;
  const int rowh = wid & 1, kh = wid >> 1;
  const int m = rowh * 16 + r;
  const int n = n0 + r;

  const uint8_t* pah = ah8 + m * Iv + kh * 1024 + q * 8;
  const uint8_t* pal = al8 + m * Iv + kh * 1024 + q * 8;
  const uint32_t* pb = wp + (size_t)(kh * 128 + q) * Hv + n;
  const float* psc = sc + kh * 8 * Hv + n;

  f32x4 acc = {0,0,0,0};
  for (int g = 0; g < 8; ++g) {
    f32x4 t0 = {0,0,0,0};
    #pragma unroll
    for (int st = 0; st < 4; ++st) {
      const int koff = g * 128 + st * 32;
      long Ah = *(const long*)(pah + koff);
      long Al = *(const long*)(pal + koff);
      long Bf = dec8(pb[(size_t)(g * 16 + st * 4) * Hv]);
      t0 = __builtin_amdgcn_mfma_f32_16x16x32_fp8_fp8(Ah, Bf, t0, 0, 0, 0);
      t0 = __builtin_amdgcn_mfma_f32_16x16x32_fp8_fp8(Al, Bf, t0, 0, 0, 0);
    }
    const float sv = psc[g * Hv];
    #pragma unroll
    for (int j = 0; j < 4; ++j) acc[j] = fmaf(sv, t0[j], acc[j]);
  }
  #pragma unroll
  for (int j = 0; j < 4; ++j)
    lds[kh * 512 + (rowh * 16 + q * 4 + j) * 16 + r] = acc[j];
  __syncthreads();
  const int i = threadIdx.x;
  #pragma unroll
  for (int o2 = 0; o2 < 2; ++o2) {
    const int idx = i + o2 * 256;
    const float v = lds[idx] + lds[512 + idx];
    out[(idx >> 4) * N1 + n0 + (idx & 15)] = v;
  }
}

// ---------------------------------------------------------------------------
extern "C" void kernel_launch(void* const* d_in, const int* in_sizes, int n_in,
                              void* d_out, int out_size, void* d_ws, size_t ws_size,
                              hipStream_t stream) {
  // Harness promotes float16 tensors to float32 (dtype map: bf16/f32/int only;
  // output rule "bfloat16 -> bf16*, else float*"). So x, scales, out are f32.
  const float*    x   = (const float*)d_in[0];      // f32 [32,4096]
  const uint32_t* gup = (const uint32_t*)d_in[1];   // [512,4096] packed fp4
  const float*    gus = (const float*)d_in[2];      // f32 [32,4096]
  const uint32_t* dnp = (const uint32_t*)d_in[3];   // [256,4096] packed fp4
  const float*    dns = (const float*)d_in[4];      // f32 [16,4096]

  float*    hpart = (float*)d_ws;                                 // [4][32][4096] f32 = 2 MiB
  uint8_t*  xh    = (uint8_t*)d_ws + 4*Bv*N1*sizeof(float);       // 128 KiB
  uint8_t*  xl    = xh + Bv*Hv;                                   // 128 KiB
  uint8_t*  a8h   = xl + Bv*Hv;                                   // 64 KiB
  uint8_t*  a8l   = a8h + Bv*Iv;                                  // 64 KiB

  k_prep  <<< 64, 256, 0, stream>>>(x, (uint32_t*)xh, (uint32_t*)xl);
  k_gateup<<<256, 256, 0, stream>>>(xh, xl, gup, gus, hpart);
  k_swiglu<<< 64, 256, 0, stream>>>(hpart, (uint32_t*)a8h, (uint32_t*)a8l);
  k_down  <<<256, 256, 0, stream>>>(a8h, a8l, dnp, dns, (float*)d_out);
}

// Round 5
// 96.676 us; speedup vs baseline: 1.0980x; 1.0980x over previous
//
#include <hip/hip_runtime.h>
#include <cstdint>

typedef float f32x4 __attribute__((ext_vector_type(4)));
typedef unsigned short u16;

constexpr int Bv = 32;      // batch rows (M)
constexpr int Hv = 4096;    // hidden (K1, N2)
constexpr int Iv = 2048;    // intermediate
constexpr int N1 = 4096;    // 2*I

// ---------------------------------------------------------------------------
// fp4 e2m1 word (8 nibbles, LSB-first along K) -> 8 fp8 e4m3 bytes (k-order)
// Magnitude LUT (idx 0-7): 0x00,0x30,0x38,0x3C,0x40,0x44,0x48,0x4C; sign->bit7.
// 7 VALU per word.
// ---------------------------------------------------------------------------
__device__ __forceinline__ long dec8(uint32_t w) {
  uint32_t lo = w & 0x07070707u;          // mag idx n0,n2,n4,n6
  uint32_t hi = (w >> 4) & 0x07070707u;   // mag idx n1,n3,n5,n7
  uint32_t me = __builtin_amdgcn_perm(0x4C484440u, 0x3C383000u, lo);
  uint32_t mo = __builtin_amdgcn_perm(0x4C484440u, 0x3C383000u, hi);
  uint32_t e  = me | ((w & 0x08080808u) << 4);   // even nibbles + sign
  uint32_t o  = mo | (w & 0x80808080u);          // odd nibbles + sign
  uint32_t d0 = __builtin_amdgcn_perm(o, e, 0x05010400u);  // n0,n1,n2,n3
  uint32_t d1 = __builtin_amdgcn_perm(o, e, 0x07030602u);  // n4,n5,n6,n7
  return (long)(((uint64_t)d1 << 32) | d0);
}

// ---------------------------------------------------------------------------
// K0: x f32 [32,4096] -> two fp8(e4m3) planes: xh = fp8(x), xl = fp8(x-xh).
// Two-term split keeps activation quantization error ~0.4%.
// ---------------------------------------------------------------------------
__global__ __launch_bounds__(256) void k_prep(const float* __restrict__ x,
                                              uint32_t* __restrict__ xh,
                                              uint32_t* __restrict__ xl) {
  const int t = blockIdx.x * 256 + threadIdx.x;   // 16384 threads, 8 elems each
  const float* p = x + t * 8;
  f32x4 v0 = *(const f32x4*)p;
  f32x4 v1 = *(const f32x4*)(p + 4);
  float f[8] = {v0[0], v0[1], v0[2], v0[3], v1[0], v1[1], v1[2], v1[3]};
  uint32_t h0 = 0, h1 = 0;
  h0 = __builtin_amdgcn_cvt_pk_fp8_f32(f[0], f[1], h0, false);
  h0 = __builtin_amdgcn_cvt_pk_fp8_f32(f[2], f[3], h0, true);
  h1 = __builtin_amdgcn_cvt_pk_fp8_f32(f[4], f[5], h1, false);
  h1 = __builtin_amdgcn_cvt_pk_fp8_f32(f[6], f[7], h1, true);
  float r[8];
  r[0] = f[0] - __builtin_amdgcn_cvt_f32_fp8(h0, 0);
  r[1] = f[1] - __builtin_amdgcn_cvt_f32_fp8(h0, 1);
  r[2] = f[2] - __builtin_amdgcn_cvt_f32_fp8(h0, 2);
  r[3] = f[3] - __builtin_amdgcn_cvt_f32_fp8(h0, 3);
  r[4] = f[4] - __builtin_amdgcn_cvt_f32_fp8(h1, 0);
  r[5] = f[5] - __builtin_amdgcn_cvt_f32_fp8(h1, 1);
  r[6] = f[6] - __builtin_amdgcn_cvt_f32_fp8(h1, 2);
  r[7] = f[7] - __builtin_amdgcn_cvt_f32_fp8(h1, 3);
  uint32_t l0 = 0, l1 = 0;
  l0 = __builtin_amdgcn_cvt_pk_fp8_f32(r[0], r[1], l0, false);
  l0 = __builtin_amdgcn_cvt_pk_fp8_f32(r[2], r[3], l0, true);
  l1 = __builtin_amdgcn_cvt_pk_fp8_f32(r[4], r[5], l1, false);
  l1 = __builtin_amdgcn_cvt_pk_fp8_f32(r[6], r[7], l1, true);
  xh[t*2] = h0; xh[t*2+1] = h1;
  xl[t*2] = l0; xl[t*2+1] = l1;
}

// ---------------------------------------------------------------------------
// K1: hpart[kq][32][4096] = x[32, kq-eighth] @ dequant(W_gu)  (f32 partials)
// 512 wgs: 64-col n-tile x K-eighth(512). 4 waves: colsub(2) x rowhalf(2).
// 2 wgs/CU, 2 waves/SIMD. Fully-unrolled 4-group loop -> loads front-loaded.
// Per 128-group: 4 K32 MFMA steps (hi+lo) into temp, then acc += scale*temp.
// ---------------------------------------------------------------------------
__global__ __launch_bounds__(256) void k_gateup(
    const uint8_t* __restrict__ xh, const uint8_t* __restrict__ xl,
    const uint32_t* __restrict__ wp, const float* __restrict__ sc,
    float* __restrict__ hp) {
  const int nt = blockIdx.x >> 3;          // 0..63
  const int kq = blockIdx.x & 7;           // K eighth
  const int wid = threadIdx.x >> 6, lane = threadIdx.x & 63;
  const int q = lane >> 4, r = lane & 15;
  const int colsub = wid & 1, rowh = wid >> 1;
  const int n0 = nt * 64 + colsub * 32;
  const int nA = n0 + r, nB = n0 + 16 + r;
  const int m  = rowh * 16 + r;

  const uint8_t* pah = xh + m * Hv + kq * 512 + q * 8;
  const uint8_t* pal = xl + m * Hv + kq * 512 + q * 8;
  const uint32_t* pb = wp + (size_t)(kq * 64 + q) * N1;
  const float* psc = sc + kq * 4 * N1;

  f32x4 accA = {0,0,0,0}, accB = {0,0,0,0};

  #pragma unroll
  for (int g = 0; g < 4; ++g) {            // 4 scale groups of 128
    f32x4 tA = {0,0,0,0}, tB = {0,0,0,0};
    #pragma unroll
    for (int st = 0; st < 4; ++st) {       // 4 x K=32 MFMA steps
      const int koff = g * 128 + st * 32;
      long Ah = *(const long*)(pah + koff);
      long Al = *(const long*)(pal + koff);
      const uint32_t* b = pb + (size_t)(g * 16 + st * 4) * N1;
      long BA = dec8(b[nA]);
      long BB = dec8(b[nB]);
      tA = __builtin_amdgcn_mfma_f32_16x16x32_fp8_fp8(Ah, BA, tA, 0, 0, 0);
      tA = __builtin_amdgcn_mfma_f32_16x16x32_fp8_fp8(Al, BA, tA, 0, 0, 0);
      tB = __builtin_amdgcn_mfma_f32_16x16x32_fp8_fp8(Ah, BB, tB, 0, 0, 0);
      tB = __builtin_amdgcn_mfma_f32_16x16x32_fp8_fp8(Al, BB, tB, 0, 0, 0);
    }
    const float sA = psc[g * N1 + nA];
    const float sB = psc[g * N1 + nB];
    #pragma unroll
    for (int j = 0; j < 4; ++j) {
      accA[j] = fmaf(sA, tA[j], accA[j]);
      accB[j] = fmaf(sB, tB[j], accB[j]);
    }
  }
  float* o = hp + (size_t)kq * (Bv * N1);
  #pragma unroll
  for (int j = 0; j < 4; ++j) {
    const int row = rowh * 16 + q * 4 + j;
    o[row * N1 + nA] = accA[j];
    o[row * N1 + nB] = accB[j];
  }
}

// ---------------------------------------------------------------------------
// K2: SwiGLU over 8 f32 partial planes -> two fp8 planes of act [32,2048].
// Clamp to +-440 (OCP e4m3 overflow->NaN armor; true |act| <~ 25).
// ---------------------------------------------------------------------------
__global__ __launch_bounds__(256) void k_swiglu(const float* __restrict__ hp,
                                                uint32_t* __restrict__ ah,
                                                uint32_t* __restrict__ al) {
  const int t = blockIdx.x * 256 + threadIdx.x;  // 16384 threads, 4 elems each
  const int m = t >> 9;
  const int c = (t & 511) * 4;
  constexpr int P = Bv * N1;
  const float* pg = hp + m * N1 + c;
  const float* pu = pg + Iv;
  f32x4 g = {0,0,0,0}, u = {0,0,0,0};
  #pragma unroll
  for (int p = 0; p < 8; ++p) {
    g += *(const f32x4*)(pg + p * P);
    u += *(const f32x4*)(pu + p * P);
  }
  float a[4];
  #pragma unroll
  for (int j = 0; j < 4; ++j) {
    float gv = g[j];
    float av = gv / (1.0f + __expf(-gv)) * u[j];
    a[j] = fminf(fmaxf(av, -440.0f), 440.0f);
  }
  uint32_t h = 0;
  h = __builtin_amdgcn_cvt_pk_fp8_f32(a[0], a[1], h, false);
  h = __builtin_amdgcn_cvt_pk_fp8_f32(a[2], a[3], h, true);
  float r0 = a[0] - __builtin_amdgcn_cvt_f32_fp8(h, 0);
  float r1 = a[1] - __builtin_amdgcn_cvt_f32_fp8(h, 1);
  float r2 = a[2] - __builtin_amdgcn_cvt_f32_fp8(h, 2);
  float r3 = a[3] - __builtin_amdgcn_cvt_f32_fp8(h, 3);
  uint32_t l = 0;
  l = __builtin_amdgcn_cvt_pk_fp8_f32(r0, r1, l, false);
  l = __builtin_amdgcn_cvt_pk_fp8_f32(r2, r3, l, true);
  ah[t] = h; al[t] = l;
}

// ---------------------------------------------------------------------------
// K3: out f32 [32][4096] = act[32,2048] @ dequant(W_down).
// 256 wgs x 512 thr. 8 waves: rowhalf(2) x K-quarter(4 x 512). LDS-reduce.
// ---------------------------------------------------------------------------
__global__ __launch_bounds__(512) void k_down(
    const uint8_t* __restrict__ ah8, const uint8_t* __restrict__ al8,
    const uint32_t* __restrict__ wp, const float* __restrict__ sc,
    float* __restrict__ out) {
  __shared__ float lds[2048];
  const int n0 = blockIdx.x * 16;
  const int wid = threadIdx.x >> 6, lane = threadIdx.x & 63;
  const int q = lane >> 4, r = lane & 15;
  const int rowh = wid & 1, kq = wid >> 1;    // kq: 0..3
  const int m = rowh * 16 + r;
  const int n = n0 + r;

  const uint8_t* pah = ah8 + m * Iv + kq * 512 + q * 8;
  const uint8_t* pal = al8 + m * Iv + kq * 512 + q * 8;
  const uint32_t* pb = wp + (size_t)(kq * 64 + q) * Hv + n;
  const float* psc = sc + kq * 4 * Hv + n;

  f32x4 acc = {0,0,0,0};
  #pragma unroll
  for (int g = 0; g < 4; ++g) {
    f32x4 t0 = {0,0,0,0};
    #pragma unroll
    for (int st = 0; st < 4; ++st) {
      const int koff = g * 128 + st * 32;
      long Ah = *(const long*)(pah + koff);
      long Al = *(const long*)(pal + koff);
      long Bf = dec8(pb[(size_t)(g * 16 + st * 4) * Hv]);
      t0 = __builtin_amdgcn_mfma_f32_16x16x32_fp8_fp8(Ah, Bf, t0, 0, 0, 0);
      t0 = __builtin_amdgcn_mfma_f32_16x16x32_fp8_fp8(Al, Bf, t0, 0, 0, 0);
    }
    const float sv = psc[g * Hv];
    #pragma unroll
    for (int j = 0; j < 4; ++j) acc[j] = fmaf(sv, t0[j], acc[j]);
  }
  #pragma unroll
  for (int j = 0; j < 4; ++j)
    lds[kq * 512 + (rowh * 16 + q * 4 + j) * 16 + r] = acc[j];
  __syncthreads();
  const int i = threadIdx.x;     // 0..511, one output each
  const float v = lds[i] + lds[512 + i] + lds[1024 + i] + lds[1536 + i];
  out[(i >> 4) * N1 + n0 + (i & 15)] = v;
}

// ---------------------------------------------------------------------------
extern "C" void kernel_launch(void* const* d_in, const int* in_sizes, int n_in,
                              void* d_out, int out_size, void* d_ws, size_t ws_size,
                              hipStream_t stream) {
  // Harness promotes float16 tensors to float32. x, scales, out are f32.
  const float*    x   = (const float*)d_in[0];      // f32 [32,4096]
  const uint32_t* gup = (const uint32_t*)d_in[1];   // [512,4096] packed fp4
  const float*    gus = (const float*)d_in[2];      // f32 [32,4096]
  const uint32_t* dnp = (const uint32_t*)d_in[3];   // [256,4096] packed fp4
  const float*    dns = (const float*)d_in[4];      // f32 [16,4096]

  float*    hpart = (float*)d_ws;                                 // [8][32][4096] f32 = 4 MiB
  uint8_t*  xh    = (uint8_t*)d_ws + 8*(size_t)Bv*N1*sizeof(float);
  uint8_t*  xl    = xh + Bv*Hv;                                   // 128 KiB each
  uint8_t*  a8h   = xl + Bv*Hv;
  uint8_t*  a8l   = a8h + Bv*Iv;                                  // 64 KiB each

  k_prep  <<< 64, 256, 0, stream>>>(x, (uint32_t*)xh, (uint32_t*)xl);
  k_gateup<<<512, 256, 0, stream>>>(xh, xl, gup, gus, hpart);
  k_swiglu<<< 64, 256, 0, stream>>>(hpart, (uint32_t*)a8h, (uint32_t*)a8l);
  k_down  <<<256, 512, 0, stream>>>(a8h, a8l, dnp, dns, (float*)d_out);
}

// Round 6
// 93.349 us; speedup vs baseline: 1.1371x; 1.0356x over previous
//
#include <hip/hip_runtime.h>
#include <cstdint>

typedef float f32x4 __attribute__((ext_vector_type(4)));

constexpr int Bv = 32;      // batch rows (M)
constexpr int Hv = 4096;    // hidden (K1, N2)
constexpr int Iv = 2048;    // intermediate
constexpr int N1 = 4096;    // 2*I

// ---------------------------------------------------------------------------
// fp4 e2m1 word (8 nibbles, LSB-first along K) -> 8 fp8 e4m3 bytes (k-order)
// Magnitude LUT (idx 0-7): 0x00,0x30,0x38,0x3C,0x40,0x44,0x48,0x4C; sign->bit7.
// 7 VALU per word.
// ---------------------------------------------------------------------------
__device__ __forceinline__ long dec8(uint32_t w) {
  uint32_t lo = w & 0x07070707u;          // mag idx n0,n2,n4,n6
  uint32_t hi = (w >> 4) & 0x07070707u;   // mag idx n1,n3,n5,n7
  uint32_t me = __builtin_amdgcn_perm(0x4C484440u, 0x3C383000u, lo);
  uint32_t mo = __builtin_amdgcn_perm(0x4C484440u, 0x3C383000u, hi);
  uint32_t e  = me | ((w & 0x08080808u) << 4);   // even nibbles + sign
  uint32_t o  = mo | (w & 0x80808080u);          // odd nibbles + sign
  uint32_t d0 = __builtin_amdgcn_perm(o, e, 0x05010400u);  // n0,n1,n2,n3
  uint32_t d1 = __builtin_amdgcn_perm(o, e, 0x07030602u);  // n4,n5,n6,n7
  return (long)(((uint64_t)d1 << 32) | d0);
}

// ---------------------------------------------------------------------------
// K0: x f32 [32,4096] -> two fp8(e4m3) planes: xh = fp8(x), xl = fp8(x-xh).
// Two-term split keeps activation quantization error ~0.4%.
// ---------------------------------------------------------------------------
__global__ __launch_bounds__(256) void k_prep(const float* __restrict__ x,
                                              uint32_t* __restrict__ xh,
                                              uint32_t* __restrict__ xl) {
  const int t = blockIdx.x * 256 + threadIdx.x;   // 16384 threads, 8 elems each
  const float* p = x + t * 8;
  f32x4 v0 = *(const f32x4*)p;
  f32x4 v1 = *(const f32x4*)(p + 4);
  float f[8] = {v0[0], v0[1], v0[2], v0[3], v1[0], v1[1], v1[2], v1[3]};
  uint32_t h0 = 0, h1 = 0;
  h0 = __builtin_amdgcn_cvt_pk_fp8_f32(f[0], f[1], h0, false);
  h0 = __builtin_amdgcn_cvt_pk_fp8_f32(f[2], f[3], h0, true);
  h1 = __builtin_amdgcn_cvt_pk_fp8_f32(f[4], f[5], h1, false);
  h1 = __builtin_amdgcn_cvt_pk_fp8_f32(f[6], f[7], h1, true);
  float r[8];
  r[0] = f[0] - __builtin_amdgcn_cvt_f32_fp8(h0, 0);
  r[1] = f[1] - __builtin_amdgcn_cvt_f32_fp8(h0, 1);
  r[2] = f[2] - __builtin_amdgcn_cvt_f32_fp8(h0, 2);
  r[3] = f[3] - __builtin_amdgcn_cvt_f32_fp8(h0, 3);
  r[4] = f[4] - __builtin_amdgcn_cvt_f32_fp8(h1, 0);
  r[5] = f[5] - __builtin_amdgcn_cvt_f32_fp8(h1, 1);
  r[6] = f[6] - __builtin_amdgcn_cvt_f32_fp8(h1, 2);
  r[7] = f[7] - __builtin_amdgcn_cvt_f32_fp8(h1, 3);
  uint32_t l0 = 0, l1 = 0;
  l0 = __builtin_amdgcn_cvt_pk_fp8_f32(r[0], r[1], l0, false);
  l0 = __builtin_amdgcn_cvt_pk_fp8_f32(r[2], r[3], l0, true);
  l1 = __builtin_amdgcn_cvt_pk_fp8_f32(r[4], r[5], l1, false);
  l1 = __builtin_amdgcn_cvt_pk_fp8_f32(r[6], r[7], l1, true);
  xh[t*2] = h0; xh[t*2+1] = h1;
  xl[t*2] = l0; xl[t*2+1] = l1;
}

// ---------------------------------------------------------------------------
// K1: hp[kh][32][4096] = x[32, K-half] @ dequant(W_gu)  (f32 partials)
// 256 wgs x 1024 thr: wg = 32-col tile x K-half(2048). 16 waves = ksub, each
// wave owns exactly ONE 128-wide scale group: result = scale * (4-step MFMA).
// Wave covers all 32 rows (two 16-row tiles) reusing each dec8'd B fragment
// -> B fetched exactly once device-wide. 16-way LDS reduce -> one plane.
// Layouts: A[m=lane&15][k=q*8+j]; B[k=q*8+j][n=lane&15]; C col=r,row=q*4+reg.
// ---------------------------------------------------------------------------
__global__ __launch_bounds__(1024, 4) void k_gateup(
    const uint8_t* __restrict__ xh, const uint8_t* __restrict__ xl,
    const uint32_t* __restrict__ wp, const float* __restrict__ sc,
    float* __restrict__ hp) {
  __shared__ float lds[16 * 1024];
  const int nt = blockIdx.x >> 1;          // 0..127 (32-col tile)
  const int kh = blockIdx.x & 1;           // K half
  const int wid = threadIdx.x >> 6, lane = threadIdx.x & 63;
  const int q = lane >> 4, r = lane & 15;
  const int n0 = nt * 32;
  const int nA = n0 + r, nB = n0 + 16 + r;

  const int koff = kh * 2048 + wid * 128 + q * 8;    // fp8-elem offset
  const uint8_t* pa0h = xh + r * Hv + koff;
  const uint8_t* pa0l = xl + r * Hv + koff;
  const uint8_t* pa1h = xh + (r + 16) * Hv + koff;
  const uint8_t* pa1l = xl + (r + 16) * Hv + koff;
  const uint32_t* pbA = wp + (size_t)(kh * 256 + wid * 16 + q) * N1 + nA;
  const uint32_t* pbB = pbA + 16;

  f32x4 t00 = {0,0,0,0}, t01 = {0,0,0,0}, t10 = {0,0,0,0}, t11 = {0,0,0,0};
  #pragma unroll
  for (int st = 0; st < 4; ++st) {         // 4 x K=32 steps = one group
    long A0h = *(const long*)(pa0h + st * 32);
    long A0l = *(const long*)(pa0l + st * 32);
    long A1h = *(const long*)(pa1h + st * 32);
    long A1l = *(const long*)(pa1l + st * 32);
    long BA = dec8(pbA[(size_t)st * 4 * N1]);
    long BB = dec8(pbB[(size_t)st * 4 * N1]);
    t00 = __builtin_amdgcn_mfma_f32_16x16x32_fp8_fp8(A0h, BA, t00, 0, 0, 0);
    t00 = __builtin_amdgcn_mfma_f32_16x16x32_fp8_fp8(A0l, BA, t00, 0, 0, 0);
    t01 = __builtin_amdgcn_mfma_f32_16x16x32_fp8_fp8(A0h, BB, t01, 0, 0, 0);
    t01 = __builtin_amdgcn_mfma_f32_16x16x32_fp8_fp8(A0l, BB, t01, 0, 0, 0);
    t10 = __builtin_amdgcn_mfma_f32_16x16x32_fp8_fp8(A1h, BA, t10, 0, 0, 0);
    t10 = __builtin_amdgcn_mfma_f32_16x16x32_fp8_fp8(A1l, BA, t10, 0, 0, 0);
    t11 = __builtin_amdgcn_mfma_f32_16x16x32_fp8_fp8(A1h, BB, t11, 0, 0, 0);
    t11 = __builtin_amdgcn_mfma_f32_16x16x32_fp8_fp8(A1l, BB, t11, 0, 0, 0);
  }
  const int g = kh * 16 + wid;             // this wave's scale group
  const float sA = sc[g * N1 + nA];
  const float sB = sc[g * N1 + nB];
  float* my = lds + wid * 1024;
  #pragma unroll
  for (int j = 0; j < 4; ++j) {
    const int rw = q * 4 + j;
    my[rw * 32 + r]             = sA * t00[j];
    my[rw * 32 + 16 + r]        = sB * t01[j];
    my[(16 + rw) * 32 + r]      = sA * t10[j];
    my[(16 + rw) * 32 + 16 + r] = sB * t11[j];
  }
  __syncthreads();
  const int i = threadIdx.x;               // 1024 outputs (32x32)
  float sum = 0.f;
  #pragma unroll
  for (int w = 0; w < 16; ++w) sum += lds[w * 1024 + i];
  hp[(size_t)kh * (Bv * N1) + (i >> 5) * N1 + n0 + (i & 31)] = sum;
}

// ---------------------------------------------------------------------------
// K2: SwiGLU over 2 f32 partial planes -> two fp8 planes of act [32,2048].
// Clamp to +-440 (OCP e4m3 overflow->NaN armor; true |act| <~ 25).
// ---------------------------------------------------------------------------
__global__ __launch_bounds__(256) void k_swiglu(const float* __restrict__ hp,
                                                uint32_t* __restrict__ ah,
                                                uint32_t* __restrict__ al) {
  const int t = blockIdx.x * 256 + threadIdx.x;  // 16384 threads, 4 elems each
  const int m = t >> 9;
  const int c = (t & 511) * 4;
  constexpr int P = Bv * N1;
  const float* pg = hp + m * N1 + c;
  const float* pu = pg + Iv;
  f32x4 g = *(const f32x4*)pg + *(const f32x4*)(pg + P);
  f32x4 u = *(const f32x4*)pu + *(const f32x4*)(pu + P);
  float a[4];
  #pragma unroll
  for (int j = 0; j < 4; ++j) {
    float gv = g[j];
    float av = gv / (1.0f + __expf(-gv)) * u[j];
    a[j] = fminf(fmaxf(av, -440.0f), 440.0f);
  }
  uint32_t h = 0;
  h = __builtin_amdgcn_cvt_pk_fp8_f32(a[0], a[1], h, false);
  h = __builtin_amdgcn_cvt_pk_fp8_f32(a[2], a[3], h, true);
  float r0 = a[0] - __builtin_amdgcn_cvt_f32_fp8(h, 0);
  float r1 = a[1] - __builtin_amdgcn_cvt_f32_fp8(h, 1);
  float r2 = a[2] - __builtin_amdgcn_cvt_f32_fp8(h, 2);
  float r3 = a[3] - __builtin_amdgcn_cvt_f32_fp8(h, 3);
  uint32_t l = 0;
  l = __builtin_amdgcn_cvt_pk_fp8_f32(r0, r1, l, false);
  l = __builtin_amdgcn_cvt_pk_fp8_f32(r2, r3, l, true);
  ah[t] = h; al[t] = l;
}

// ---------------------------------------------------------------------------
// K3: out f32 [32][4096] = act[32,2048] @ dequant(W_down).
// 256 wgs x 1024 thr: wg = 16-col tile x full K(2048). 16 waves = one scale
// group each; both row-tiles per wave; 16-way LDS reduce; direct f32 out.
// ---------------------------------------------------------------------------
__global__ __launch_bounds__(1024, 4) void k_down(
    const uint8_t* __restrict__ ah8, const uint8_t* __restrict__ al8,
    const uint32_t* __restrict__ wp, const float* __restrict__ sc,
    float* __restrict__ out) {
  __shared__ float lds[16 * 512];
  const int n0 = blockIdx.x * 16;
  const int wid = threadIdx.x >> 6, lane = threadIdx.x & 63;
  const int q = lane >> 4, r = lane & 15;
  const int n = n0 + r;

  const int koff = wid * 128 + q * 8;
  const uint8_t* pa0h = ah8 + r * Iv + koff;
  const uint8_t* pa0l = al8 + r * Iv + koff;
  const uint8_t* pa1h = ah8 + (r + 16) * Iv + koff;
  const uint8_t* pa1l = al8 + (r + 16) * Iv + koff;
  const uint32_t* pb = wp + (size_t)(wid * 16 + q) * Hv + n;

  f32x4 t0 = {0,0,0,0}, t1 = {0,0,0,0};
  #pragma unroll
  for (int st = 0; st < 4; ++st) {
    long A0h = *(const long*)(pa0h + st * 32);
    long A0l = *(const long*)(pa0l + st * 32);
    long A1h = *(const long*)(pa1h + st * 32);
    long A1l = *(const long*)(pa1l + st * 32);
    long Bf = dec8(pb[(size_t)st * 4 * Hv]);
    t0 = __builtin_amdgcn_mfma_f32_16x16x32_fp8_fp8(A0h, Bf, t0, 0, 0, 0);
    t0 = __builtin_amdgcn_mfma_f32_16x16x32_fp8_fp8(A0l, Bf, t0, 0, 0, 0);
    t1 = __builtin_amdgcn_mfma_f32_16x16x32_fp8_fp8(A1h, Bf, t1, 0, 0, 0);
    t1 = __builtin_amdgcn_mfma_f32_16x16x32_fp8_fp8(A1l, Bf, t1, 0, 0, 0);
  }
  const float sv = sc[wid * Hv + n];
  float* my = lds + wid * 512;
  #pragma unroll
  for (int j = 0; j < 4; ++j) {
    const int rw = q * 4 + j;
    my[rw * 16 + r]        = sv * t0[j];
    my[(16 + rw) * 16 + r] = sv * t1[j];
  }
  __syncthreads();
  const int i = threadIdx.x;
  if (i < 512) {                            // 512 outputs (32x16)
    float sum = 0.f;
    #pragma unroll
    for (int w = 0; w < 16; ++w) sum += lds[w * 512 + i];
    out[(i >> 4) * N1 + n0 + (i & 15)] = sum;
  }
}

// ---------------------------------------------------------------------------
extern "C" void kernel_launch(void* const* d_in, const int* in_sizes, int n_in,
                              void* d_out, int out_size, void* d_ws, size_t ws_size,
                              hipStream_t stream) {
  // Harness promotes float16 tensors to float32. x, scales, out are f32.
  const float*    x   = (const float*)d_in[0];      // f32 [32,4096]
  const uint32_t* gup = (const uint32_t*)d_in[1];   // [512,4096] packed fp4
  const float*    gus = (const float*)d_in[2];      // f32 [32,4096]
  const uint32_t* dnp = (const uint32_t*)d_in[3];   // [256,4096] packed fp4
  const float*    dns = (const float*)d_in[4];      // f32 [16,4096]

  float*    hpart = (float*)d_ws;                                 // [2][32][4096] f32 = 1 MiB
  uint8_t*  xh    = (uint8_t*)d_ws + 2*(size_t)Bv*N1*sizeof(float);
  uint8_t*  xl    = xh + Bv*Hv;                                   // 128 KiB each
  uint8_t*  a8h   = xl + Bv*Hv;
  uint8_t*  a8l   = a8h + Bv*Iv;                                  // 64 KiB each

  k_prep  <<< 64,  256, 0, stream>>>(x, (uint32_t*)xh, (uint32_t*)xl);
  k_gateup<<<256, 1024, 0, stream>>>(xh, xl, gup, gus, hpart);
  k_swiglu<<< 64,  256, 0, stream>>>(hpart, (uint32_t*)a8h, (uint32_t*)a8l);
  k_down  <<<256, 1024, 0, stream>>>(a8h, a8l, dnp, dns, (float*)d_out);
}